// Round 2
// baseline (481.162 us; speedup 1.0000x reference)
//
#include <hip/hip_runtime.h>
#include <math.h>

// MoE router: T=16384 tokens, H=4096, E=8 experts, K=2.
// d_out layout (float32, flat, reference return order):
//   [0      , 32768 )  routing_weights  (T,2)
//   [32768  , 65536 )  selected_experts (T,2)  stored as float(index)
//   [65536  , 196608)  router_logits    (T,8)
//   [196608 ]          aux_loss (scalar)
// d_ws: 16 rows x NBLOCKS of per-block partials (plain stores, no init):
//   row e   (e=0..7):  sum of softmax probs for expert e
//   row 8+e (e=0..7):  top-1 counts for expert e
//
// R2 change: TOK_PER_WAVE 8->4 to raise occupancy. R1's depth-1 A/B pipeline
// (kept) needed ~222 VGPR at TOK=8 -> stuck at 2 waves/SIMD; per-SIMD compute
// (512cy) < NT-load latency (~900cy) left ~40% stall. TOK=4 halves acc (64->32)
// and hidden buffers (32->16 each): ~158 VGPR -> launch_bounds(256,3) -> 3
// waves/SIMD (12/CU, +50% TLP). Grid 512->1024 blocks. Gate L2 traffic doubles
// to 512 MB/pass - trivial vs 34.5 TB/s L2. Butterfly reduced to 32 values per
// 32-lane half + final xor(32) fold.

#define T_TOKENS 16384
#define H_DIM    4096
#define NEXP     8
#define H4       (H_DIM / 4)   // 1024 float4 per row
#define ITERS    (H4 / 64)     // 16 float4 chunks per lane per token
#define TOK_PER_WAVE 4
#define WAVES_PER_BLOCK 4
#define TOK_PER_BLOCK (TOK_PER_WAVE * WAVES_PER_BLOCK)  // 16
#define NBLOCKS (T_TOKENS / TOK_PER_BLOCK)              // 1024

#define OFF_RW  0
#define OFF_SE  32768
#define OFF_LG  65536
#define OFF_AUX 196608

// Native vector type usable with __builtin_nontemporal_load (HIP's float4 is
// a class and is rejected by the builtin).
typedef float vfloat4 __attribute__((ext_vector_type(4)));

// Halving butterfly step: value set of size 2N -> N, summing over lane pairs
// differing in bit OFFSET. Starting from 32 values r[0..31] and steps
// OFFSET=16,8,4,2,1, lane l ends holding the 32-lane-half sum of value (l&31).
#define RED_STEP(OFFSET, N)                                        \
  {                                                                \
    const bool hi = (lane & (OFFSET)) != 0;                        \
    _Pragma("unroll")                                              \
    for (int i = 0; i < (N); ++i) {                                \
      float send = hi ? r[i] : r[i + (N)];                         \
      float recv = __shfl_xor(send, (OFFSET), 64);                 \
      r[i] = (hi ? r[i + (N)] : r[i]) + recv;                      \
    }                                                              \
  }

// Issue the 12 loads (4 hidden NT + 8 gate) for chunk KIDX into named
// register buffers. Macro (not lambda/pointer) so SROA trivially keeps the
// arrays in registers (no runtime indexing anywhere).
#define LOAD_CHUNK(HV, G, KIDX)                                    \
  {                                                                \
    const int idx_ = lane + 64 * (KIDX);                           \
    _Pragma("unroll")                                              \
    for (int t = 0; t < TOK_PER_WAVE; ++t)                         \
      HV[t] = __builtin_nontemporal_load(                          \
          &h4p[(tokenBase + t) * H4 + idx_]);                      \
    _Pragma("unroll")                                              \
    for (int e = 0; e < NEXP; ++e)                                 \
      G[e] = g4p[e * H4 + idx_];                                   \
  }

#define COMPUTE_CHUNK(HV, G)                                       \
  {                                                                \
    _Pragma("unroll")                                              \
    for (int t = 0; t < TOK_PER_WAVE; ++t) {                       \
      _Pragma("unroll")                                            \
      for (int e = 0; e < NEXP; ++e) {                             \
        float a = r[t * NEXP + e];                                 \
        a = fmaf(HV[t].x, G[e].x, a);                              \
        a = fmaf(HV[t].y, G[e].y, a);                              \
        a = fmaf(HV[t].z, G[e].z, a);                              \
        a = fmaf(HV[t].w, G[e].w, a);                              \
        r[t * NEXP + e] = a;                                       \
      }                                                            \
    }                                                              \
  }

__global__ __launch_bounds__(256, 3)
void router_kernel(const float* __restrict__ hs, const float* __restrict__ gw,
                   float* __restrict__ out, float* __restrict__ ws) {
  __shared__ float smP[NEXP];
  __shared__ float smC[NEXP];
  if (threadIdx.x < NEXP) { smP[threadIdx.x] = 0.f; smC[threadIdx.x] = 0.f; }
  __syncthreads();

  const int lane = threadIdx.x & 63;
  const int wave = threadIdx.x >> 6;
  const int tokenBase = (blockIdx.x * WAVES_PER_BLOCK + wave) * TOK_PER_WAVE;

  const vfloat4* __restrict__ h4p = reinterpret_cast<const vfloat4*>(hs);
  const vfloat4* __restrict__ g4p = reinterpret_cast<const vfloat4*>(gw);

  float r[TOK_PER_WAVE * NEXP];  // 32 accumulators: r[t*8+e]
#pragma unroll
  for (int i = 0; i < TOK_PER_WAVE * NEXP; ++i) r[i] = 0.f;

  // Depth-1 software pipeline over the 16 k-chunks. Named A/B buffers with
  // a k+=2 loop: every register access is compile-time-indexed.
  vfloat4 hvA[TOK_PER_WAVE], gA[NEXP];
  vfloat4 hvB[TOK_PER_WAVE], gB[NEXP];

  LOAD_CHUNK(hvA, gA, 0)
  for (int k = 0; k < ITERS; k += 2) {
    LOAD_CHUNK(hvB, gB, k + 1)       // prefetch odd chunk
    COMPUTE_CHUNK(hvA, gA)           // consume even chunk (loaded last iter)
    if (k + 2 < ITERS) {
      LOAD_CHUNK(hvA, gA, k + 2)     // prefetch next even chunk
    }
    COMPUTE_CHUNK(hvB, gB)           // consume odd chunk
  }

  // 32-value butterfly within each 32-lane half: lane l ends holding the
  // half-sum of value (l&31) (token = (l&31)>>3, expert = l&7).
  RED_STEP(16, 16)
  RED_STEP(8, 8)
  RED_STEP(4, 4)
  RED_STEP(2, 2)
  float red;
  {
    const bool hi = (lane & 1) != 0;
    float send = hi ? r[0] : r[1];
    float recv = __shfl_xor(send, 1, 64);
    red = (hi ? r[1] : r[0]) + recv;
  }
  // Fold the two 32-lane halves: every lane now holds the full 64-lane sum
  // of value (lane&31).
  red += __shfl_xor(red, 32, 64);

  // Lanes 0..31 store one logit each: 128 B contiguous per wave.
  if (lane < 32) out[OFF_LG + tokenBase * NEXP + lane] = red;

  // Gather the 8 logits of this lane-group's token (source lanes 0..31 hold
  // full sums; all 64 lanes execute the shfl).
  float le[NEXP];
  const int groupBase = lane & 24;
#pragma unroll
  for (int e = 0; e < NEXP; ++e) le[e] = __shfl(red, groupBase + e, 64);

  if (lane < 32 && (lane & 7) == 0) {
    const int tok = tokenBase + (lane >> 3);
    // top-1 (strict > => lowest index wins ties, like lax.top_k)
    int i1 = 0; float m1 = le[0];
#pragma unroll
    for (int e = 1; e < NEXP; ++e) {
      if (le[e] > m1) { m1 = le[e]; i1 = e; }
    }
    int i2 = (i1 == 0) ? 1 : 0; float m2 = le[i2];
#pragma unroll
    for (int e = 0; e < NEXP; ++e) {
      if (e != i1 && le[e] > m2) { m2 = le[e]; i2 = e; }
    }
    // full softmax (max-shifted)
    float p[NEXP];
    float psum = 0.f;
#pragma unroll
    for (int e = 0; e < NEXP; ++e) { p[e] = expf(le[e] - m1); psum += p[e]; }
    const float inv = 1.0f / psum;
#pragma unroll
    for (int e = 0; e < NEXP; ++e) atomicAdd(&smP[e], p[e] * inv);
    atomicAdd(&smC[i1], 1.0f);

    // normalized top-2 routing weights: p[i1] = 1, p[i2] = exp(m2-m1)
    const float w1 = p[i1], w2 = p[i2];
    const float rs = 1.0f / (w1 + w2);
    out[OFF_RW + tok * 2 + 0] = w1 * rs;
    out[OFF_RW + tok * 2 + 1] = w2 * rs;
    out[OFF_SE + tok * 2 + 0] = (float)i1;
    out[OFF_SE + tok * 2 + 1] = (float)i2;
  }

  __syncthreads();
  // Per-block partials: row-major [16 rows][NBLOCKS]; plain stores, no
  // init needed (d_ws is poison — we overwrite every slot we later read).
  if (threadIdx.x < 2 * NEXP) {
    const float v = (threadIdx.x < NEXP) ? smP[threadIdx.x]
                                         : smC[threadIdx.x - NEXP];
    ws[threadIdx.x * NBLOCKS + blockIdx.x] = v;
  }
}

__global__ __launch_bounds__(1024)
void aux_kernel(const float* __restrict__ ws, float* __restrict__ out) {
  __shared__ float sm[2 * NEXP];
  const int lane = threadIdx.x & 63;
  const int w = threadIdx.x >> 6;  // 16 waves, one per partial row
  float s = 0.f;
#pragma unroll
  for (int i = 0; i < NBLOCKS / 64; ++i) s += ws[w * NBLOCKS + lane + 64 * i];
#pragma unroll
  for (int off = 32; off > 0; off >>= 1) s += __shfl_xor(s, off, 64);
  if (lane == 0) sm[w] = s;
  __syncthreads();
  if (threadIdx.x == 0) {
    const float invT = 1.0f / (float)T_TOKENS;
    float acc = 0.f;
#pragma unroll
    for (int e = 0; e < NEXP; ++e) {
      const float f = sm[NEXP + e] * invT;  // mean one-hot(top1)
      const float P = sm[e] * invT;         // mean probs
      acc += f * P;
    }
    out[OFF_AUX] = 0.01f * (float)NEXP * acc;
  }
}

extern "C" void kernel_launch(void* const* d_in, const int* in_sizes, int n_in,
                              void* d_out, int out_size, void* d_ws, size_t ws_size,
                              hipStream_t stream) {
  const float* hs = (const float*)d_in[0];   // (16384, 4096) f32
  const float* gw = (const float*)d_in[1];   // (8, 4096) f32
  float* out = (float*)d_out;
  float* ws  = (float*)d_ws;

  router_kernel<<<NBLOCKS, 256, 0, stream>>>(hs, gw, out, ws);
  aux_kernel<<<1, 1024, 0, stream>>>(ws, out);
}

// Round 3
// 353.637 us; speedup vs baseline: 1.3606x; 1.3606x over previous
//
#include <hip/hip_runtime.h>
#include <math.h>

// MoE router: T=16384 tokens, H=4096, E=8 experts, K=2.
// d_out layout (float32, flat, reference return order):
//   [0      , 32768 )  routing_weights  (T,2)
//   [32768  , 65536 )  selected_experts (T,2)  stored as float(index)
//   [65536  , 196608)  router_logits    (T,8)
//   [196608 ]          aux_loss (scalar)
// d_ws: 16 rows x NBLOCKS of per-block partials (plain stores, no init):
//   row e   (e=0..7):  sum of softmax probs for expert e
//   row 8+e (e=0..7):  top-1 counts for expert e
//
// R3 change: fix R2's register spill. R2 (launch_bounds(256,3), full A/B
// double-buffer of hidden AND gate) demanded ~160+ VGPR under a 170 cap ->
// allocator spilled pipeline buffers to scratch: VGPR_Count=84, WRITE_SIZE
// 332 MB of dirty scratch evictions, router 202us. R3 shrinks demand instead
// of capping: gate is L1/L2-resident (128 KB) so its ~100-200cy latency needs
// no register prefetch; only the NT hidden stream (~900cy) keeps the depth-1
// A/B prefetch. Live set ~106 VGPR under launch_bounds(256,2) (cap 256, no
// spill risk); actual usage -> 4 waves/SIMD (16/CU) organically. Per-chunk
// per-SIMD compute (4 waves x 256cy) then covers the ~900cy NT latency.

#define T_TOKENS 16384
#define H_DIM    4096
#define NEXP     8
#define H4       (H_DIM / 4)   // 1024 float4 per row
#define ITERS    (H4 / 64)     // 16 float4 chunks per lane per token
#define TOK_PER_WAVE 4
#define WAVES_PER_BLOCK 4
#define TOK_PER_BLOCK (TOK_PER_WAVE * WAVES_PER_BLOCK)  // 16
#define NBLOCKS (T_TOKENS / TOK_PER_BLOCK)              // 1024

#define OFF_RW  0
#define OFF_SE  32768
#define OFF_LG  65536
#define OFF_AUX 196608

// Native vector type usable with __builtin_nontemporal_load (HIP's float4 is
// a class and is rejected by the builtin).
typedef float vfloat4 __attribute__((ext_vector_type(4)));

// Halving butterfly step: value set of size 2N -> N, summing over lane pairs
// differing in bit OFFSET. Starting from 32 values r[0..31] and steps
// OFFSET=16,8,4,2,1, lane l ends holding the 32-lane-half sum of value (l&31).
#define RED_STEP(OFFSET, N)                                        \
  {                                                                \
    const bool hi = (lane & (OFFSET)) != 0;                        \
    _Pragma("unroll")                                              \
    for (int i = 0; i < (N); ++i) {                                \
      float send = hi ? r[i] : r[i + (N)];                         \
      float recv = __shfl_xor(send, (OFFSET), 64);                 \
      r[i] = (hi ? r[i + (N)] : r[i]) + recv;                      \
    }                                                              \
  }

// Issue the 4 hidden NT loads for chunk KIDX into a named register buffer.
#define LOAD_H(HV, KIDX)                                           \
  {                                                                \
    const int idx_ = lane + 64 * (KIDX);                           \
    _Pragma("unroll")                                              \
    for (int t = 0; t < TOK_PER_WAVE; ++t)                         \
      HV[t] = __builtin_nontemporal_load(                          \
          &h4p[(tokenBase + t) * H4 + idx_]);                      \
  }

// Load this chunk's 8 gate float4s (L1/L2-warm) and do the 128 FMAs.
#define GATE_AND_COMPUTE(HV, KIDX)                                 \
  {                                                                \
    const int idx_ = lane + 64 * (KIDX);                           \
    vfloat4 g[NEXP];                                               \
    _Pragma("unroll")                                              \
    for (int e = 0; e < NEXP; ++e) g[e] = g4p[e * H4 + idx_];      \
    _Pragma("unroll")                                              \
    for (int t = 0; t < TOK_PER_WAVE; ++t) {                       \
      _Pragma("unroll")                                            \
      for (int e = 0; e < NEXP; ++e) {                             \
        float a = r[t * NEXP + e];                                 \
        a = fmaf(HV[t].x, g[e].x, a);                              \
        a = fmaf(HV[t].y, g[e].y, a);                              \
        a = fmaf(HV[t].z, g[e].z, a);                              \
        a = fmaf(HV[t].w, g[e].w, a);                              \
        r[t * NEXP + e] = a;                                       \
      }                                                            \
    }                                                              \
  }

__global__ __launch_bounds__(256, 2)
void router_kernel(const float* __restrict__ hs, const float* __restrict__ gw,
                   float* __restrict__ out, float* __restrict__ ws) {
  __shared__ float smP[NEXP];
  __shared__ float smC[NEXP];
  if (threadIdx.x < NEXP) { smP[threadIdx.x] = 0.f; smC[threadIdx.x] = 0.f; }
  __syncthreads();

  const int lane = threadIdx.x & 63;
  const int wave = threadIdx.x >> 6;
  const int tokenBase = (blockIdx.x * WAVES_PER_BLOCK + wave) * TOK_PER_WAVE;

  const vfloat4* __restrict__ h4p = reinterpret_cast<const vfloat4*>(hs);
  const vfloat4* __restrict__ g4p = reinterpret_cast<const vfloat4*>(gw);

  float r[TOK_PER_WAVE * NEXP];  // 32 accumulators: r[t*8+e]
#pragma unroll
  for (int i = 0; i < TOK_PER_WAVE * NEXP; ++i) r[i] = 0.f;

  // Depth-1 pipeline on the HIDDEN stream only. Named A/B buffers with a
  // k+=2 loop: every register access is compile-time-indexed. Gate is
  // loaded inside each compute step (cache-warm, short latency).
  vfloat4 hvA[TOK_PER_WAVE], hvB[TOK_PER_WAVE];

  LOAD_H(hvA, 0)
  for (int k = 0; k < ITERS; k += 2) {
    LOAD_H(hvB, k + 1)              // prefetch odd hidden chunk
    GATE_AND_COMPUTE(hvA, k)        // consume even chunk (loaded last iter)
    if (k + 2 < ITERS) {
      LOAD_H(hvA, k + 2)            // prefetch next even hidden chunk
    }
    GATE_AND_COMPUTE(hvB, k + 1)    // consume odd chunk
  }

  // 32-value butterfly within each 32-lane half: lane l ends holding the
  // half-sum of value (l&31) (token = (l&31)>>3, expert = l&7).
  RED_STEP(16, 16)
  RED_STEP(8, 8)
  RED_STEP(4, 4)
  RED_STEP(2, 2)
  float red;
  {
    const bool hi = (lane & 1) != 0;
    float send = hi ? r[0] : r[1];
    float recv = __shfl_xor(send, 1, 64);
    red = (hi ? r[1] : r[0]) + recv;
  }
  // Fold the two 32-lane halves: every lane now holds the full 64-lane sum
  // of value (lane&31).
  red += __shfl_xor(red, 32, 64);

  // Lanes 0..31 store one logit each: 128 B contiguous per wave.
  if (lane < 32) out[OFF_LG + tokenBase * NEXP + lane] = red;

  // Gather the 8 logits of this lane-group's token (source lanes 0..31 hold
  // full sums; all 64 lanes execute the shfl).
  float le[NEXP];
  const int groupBase = lane & 24;
#pragma unroll
  for (int e = 0; e < NEXP; ++e) le[e] = __shfl(red, groupBase + e, 64);

  if (lane < 32 && (lane & 7) == 0) {
    const int tok = tokenBase + (lane >> 3);
    // top-1 (strict > => lowest index wins ties, like lax.top_k)
    int i1 = 0; float m1 = le[0];
#pragma unroll
    for (int e = 1; e < NEXP; ++e) {
      if (le[e] > m1) { m1 = le[e]; i1 = e; }
    }
    int i2 = (i1 == 0) ? 1 : 0; float m2 = le[i2];
#pragma unroll
    for (int e = 0; e < NEXP; ++e) {
      if (e != i1 && le[e] > m2) { m2 = le[e]; i2 = e; }
    }
    // full softmax (max-shifted)
    float p[NEXP];
    float psum = 0.f;
#pragma unroll
    for (int e = 0; e < NEXP; ++e) { p[e] = expf(le[e] - m1); psum += p[e]; }
    const float inv = 1.0f / psum;
#pragma unroll
    for (int e = 0; e < NEXP; ++e) atomicAdd(&smP[e], p[e] * inv);
    atomicAdd(&smC[i1], 1.0f);

    // normalized top-2 routing weights: p[i1] = 1, p[i2] = exp(m2-m1)
    const float w1 = p[i1], w2 = p[i2];
    const float rs = 1.0f / (w1 + w2);
    out[OFF_RW + tok * 2 + 0] = w1 * rs;
    out[OFF_RW + tok * 2 + 1] = w2 * rs;
    out[OFF_SE + tok * 2 + 0] = (float)i1;
    out[OFF_SE + tok * 2 + 1] = (float)i2;
  }

  __syncthreads();
  // Per-block partials: row-major [16 rows][NBLOCKS]; plain stores, no
  // init needed (d_ws is poison — we overwrite every slot we later read).
  if (threadIdx.x < 2 * NEXP) {
    const float v = (threadIdx.x < NEXP) ? smP[threadIdx.x]
                                         : smC[threadIdx.x - NEXP];
    ws[threadIdx.x * NBLOCKS + blockIdx.x] = v;
  }
}

__global__ __launch_bounds__(1024)
void aux_kernel(const float* __restrict__ ws, float* __restrict__ out) {
  __shared__ float sm[2 * NEXP];
  const int lane = threadIdx.x & 63;
  const int w = threadIdx.x >> 6;  // 16 waves, one per partial row
  float s = 0.f;
#pragma unroll
  for (int i = 0; i < NBLOCKS / 64; ++i) s += ws[w * NBLOCKS + lane + 64 * i];
#pragma unroll
  for (int off = 32; off > 0; off >>= 1) s += __shfl_xor(s, off, 64);
  if (lane == 0) sm[w] = s;
  __syncthreads();
  if (threadIdx.x == 0) {
    const float invT = 1.0f / (float)T_TOKENS;
    float acc = 0.f;
#pragma unroll
    for (int e = 0; e < NEXP; ++e) {
      const float f = sm[NEXP + e] * invT;  // mean one-hot(top1)
      const float P = sm[e] * invT;         // mean probs
      acc += f * P;
    }
    out[OFF_AUX] = 0.01f * (float)NEXP * acc;
  }
}

extern "C" void kernel_launch(void* const* d_in, const int* in_sizes, int n_in,
                              void* d_out, int out_size, void* d_ws, size_t ws_size,
                              hipStream_t stream) {
  const float* hs = (const float*)d_in[0];   // (16384, 4096) f32
  const float* gw = (const float*)d_in[1];   // (8, 4096) f32
  float* out = (float*)d_out;
  float* ws  = (float*)d_ws;

  router_kernel<<<NBLOCKS, 256, 0, stream>>>(hs, gw, out, ws);
  aux_kernel<<<1, 1024, 0, stream>>>(ws, out);
}